// Round 7
// baseline (219.720 us; speedup 1.0000x reference)
//
#include <hip/hip_runtime.h>
#include <hip/hip_bf16.h>
#include <stdint.h>

// Problem constants
#define T_TOK 8192   // B*S tokens
#define HID   2048
#define OUTD  2048
#define NE    8
#define RR    16
#define KAUG  2176   // 2048 + NE*RR
#define NH    128    // h columns (NE*RR)
#define NKT   34     // KAUG/64 K-tiles

typedef __bf16 bf16x8 __attribute__((ext_vector_type(8)));
typedef float  f32x4  __attribute__((ext_vector_type(4)));

#define AS1(p) ((__attribute__((address_space(1))) void*)(p))
#define AS3(p) ((__attribute__((address_space(3))) void*)(p))

__device__ inline unsigned short f2bf(float f) {
  unsigned int u = __builtin_bit_cast(unsigned int, f);
  unsigned int r = (u + 0x7fffu + ((u >> 16) & 1u)) >> 16;   // RNE
  return (unsigned short)r;
}

__device__ inline ushort4 f2bf4(float4 v) {
  ushort4 u;
  u.x = f2bf(v.x); u.y = f2bf(v.y); u.z = f2bf(v.z); u.w = f2bf(v.w);
  return u;
}

// ---- prep (VERBATIM round-1/6, proven): router + Xa core + all converts ----
__global__ __launch_bounds__(512) void k_prep(const float* __restrict__ x,
                                              const float* __restrict__ gw,
                                              const float* __restrict__ W,
                                              const float* __restrict__ Bw,
                                              const float* __restrict__ A,
                                              unsigned short* __restrict__ Xa,
                                              float* __restrict__ wte,
                                              unsigned short* __restrict__ Wa,
                                              unsigned short* __restrict__ Ag) {
  __shared__ float gws[NE * HID];     // 64 KiB
  if (blockIdx.x < 1024) {
#pragma unroll
    for (int i = 0; i < 8; ++i) {
      int idx = (i * 512 + (int)threadIdx.x) * 4;
      *(float4*)(gws + idx) = *(const float4*)(gw + idx);
    }
    __syncthreads();
    int w = threadIdx.x >> 6, lane = threadIdx.x & 63;
    int t = blockIdx.x * 8 + w;
    const float* xt = x + (size_t)t * HID;
    unsigned short* xo = Xa + (size_t)t * KAUG;
    double acc[8] = {0, 0, 0, 0, 0, 0, 0, 0};
#pragma unroll
    for (int i = 0; i < 8; ++i) {
      int k = (i * 64 + lane) * 4;
      float4 xv = *(const float4*)(xt + k);
      *(ushort4*)(xo + k) = f2bf4(xv);
#pragma unroll
      for (int e = 0; e < 8; ++e) {
        float4 gv = *(const float4*)(gws + e * HID + k);
        acc[e] += (double)xv.x * gv.x + (double)xv.y * gv.y +
                  (double)xv.z * gv.z + (double)xv.w * gv.w;
      }
    }
#pragma unroll
    for (int off = 32; off >= 1; off >>= 1)
#pragma unroll
      for (int e = 0; e < 8; ++e)
        acc[e] += __shfl_down(acc[e], off, 64);
    if (lane == 0) {
      int e0 = 0; double l0 = acc[0];
#pragma unroll
      for (int e = 1; e < 8; ++e) if (acc[e] > l0) { l0 = acc[e]; e0 = e; }
      int e1 = -1; double l1 = -1e300;
#pragma unroll
      for (int e = 0; e < 8; ++e) if (e != e0 && acc[e] > l1) { l1 = acc[e]; e1 = e; }
      double w0 = 16.0 / (1.0 + exp(l1 - l0));
      float o[8] = {0.f, 0.f, 0.f, 0.f, 0.f, 0.f, 0.f, 0.f};
      o[e0] = (float)w0;
      o[e1] = (float)(16.0 - w0);
      float4* p = (float4*)(wte + (size_t)t * 8);
      p[0] = make_float4(o[0], o[1], o[2], o[3]);
      p[1] = make_float4(o[4], o[5], o[6], o[7]);
    }
  } else {
    int b2 = blockIdx.x - 1024;
    if (b2 < 2048) {
      int tid = b2 * 512 + threadIdx.x;
      int row = tid >> 9, c = (tid & 511) << 2;
      float4 v = *(const float4*)(W + (size_t)row * HID + c);
      *(ushort4*)(Wa + (size_t)row * KAUG + c) = f2bf4(v);
    } else if (b2 < 2176) {
      int tid = (b2 - 2048) * 512 + threadIdx.x;
      int o = tid >> 5, j = (tid & 31) << 2;
      int e = j >> 4, r = j & 15;
      float4 v = *(const float4*)(Bw + (size_t)e * OUTD * RR + (size_t)o * RR + r);
      *(ushort4*)(Wa + (size_t)o * KAUG + 2048 + j) = f2bf4(v);
    } else {
      int tid = (b2 - 2176) * 512 + threadIdx.x;
      float4 v = *(const float4*)(A + (size_t)tid * 4);
      *(ushort4*)(Ag + (size_t)tid * 4) = f2bf4(v);
    }
  }
}

// ---- h-GEMM (VERBATIM round-1/6, proven): ring-of-4 counted-vmcnt ----
__global__ __launch_bounds__(256) void k_ha(const unsigned short* __restrict__ Xa,
                                            const unsigned short* __restrict__ Ag,
                                            const float* __restrict__ wte,
                                            unsigned short* __restrict__ XaW) {
  __shared__ unsigned short Xs[4][32 * 64];
  __shared__ unsigned short As[4][64 * 64];
  int tm = (blockIdx.x >> 1) * 32;
  int ch = (blockIdx.x & 1) * 64;
  int w = threadIdx.x >> 6, lane = threadIdx.x & 63;
  int lrow = lane >> 3;
  int lcol_s = (lane & 7) << 3;
  int lcol_g = ((lane & 7) ^ (lrow & 7)) << 3;

  const unsigned short* gX = Xa + (size_t)(tm + w * 8 + lrow) * KAUG + lcol_g;
  const unsigned short* gA = Ag + (size_t)(ch + w * 16 + lrow) * HID + lcol_g;
  int sxo = (w * 8 + lrow) * 64 + lcol_s;
  int sao = (w * 16 + lrow) * 64 + lcol_s;

  f32x4 acc[2] = {};

#define HA_STAGE(slot, koff) do {                                                         \
    __builtin_amdgcn_global_load_lds(AS1(gX + (koff)), AS3(&Xs[slot][0] + sxo), 16, 0, 0);\
    __builtin_amdgcn_global_load_lds(AS1(gA + (koff)), AS3(&As[slot][0] + sao), 16, 0, 0);\
    __builtin_amdgcn_global_load_lds(AS1(gA + (size_t)8 * HID + (koff)),                  \
                                     AS3(&As[slot][0] + 8 * 64 + sao), 16, 0, 0);         \
  } while (0)

#define HA_COMP(s) do {                                                                   \
    _Pragma("unroll")                                                                     \
    for (int ks = 0; ks < 2; ++ks) {                                                      \
      int kch = ks * 4 + (lane >> 4);                                                     \
      int ko = ((kch ^ (lane & 7)) << 3);                                                 \
      bf16x8 a = *(const bf16x8*)(&Xs[s][0] + ((w >> 1) * 16 + (lane & 15)) * 64 + ko);   \
      _Pragma("unroll")                                                                   \
      for (int fn = 0; fn < 2; ++fn) {                                                    \
        bf16x8 bv = *(const bf16x8*)(&As[s][0] + ((w & 1) * 32 + fn * 16 + (lane & 15)) * 64 + ko); \
        acc[fn] = __builtin_amdgcn_mfma_f32_16x16x32_bf16(a, bv, acc[fn], 0, 0, 0);       \
      }                                                                                   \
    }                                                                                     \
  } while (0)

  HA_STAGE(0, 0);
  HA_STAGE(1, 64);
  HA_STAGE(2, 128);
  for (int t = 0; t < 29; ++t) {
    asm volatile("s_waitcnt vmcnt(6)" ::: "memory");
    __builtin_amdgcn_s_barrier();
    HA_COMP(t & 3);
    __builtin_amdgcn_s_barrier();
    HA_STAGE((t + 3) & 3, (t + 3) * 64);
  }
  asm volatile("s_waitcnt vmcnt(6)" ::: "memory");
  __builtin_amdgcn_s_barrier();
  HA_COMP(1);
  asm volatile("s_waitcnt vmcnt(3)" ::: "memory");
  __builtin_amdgcn_s_barrier();
  HA_COMP(2);
  asm volatile("s_waitcnt vmcnt(0)" ::: "memory");
  __builtin_amdgcn_s_barrier();
  HA_COMP(3);
#undef HA_STAGE
#undef HA_COMP

  int q = lane >> 4;
#pragma unroll
  for (int fn = 0; fn < 2; ++fn) {
    int col = ch + (w & 1) * 32 + fn * 16 + (lane & 15);
    int e = col >> 4;
#pragma unroll
    for (int r = 0; r < 4; ++r) {
      int t = tm + (w >> 1) * 16 + q * 4 + r;
      float we = wte[(size_t)t * 8 + e];
      XaW[(size_t)t * KAUG + 2048 + col] = f2bf(we * acc[fn][r]);
    }
  }
}

// ---- main GEMM: 256x256 tile, 8 waves, 8-PHASE schedule (m201 template) ----
// Fragment math / swizzle / staging addresses / epilogue VERBATIM from the
// R6 kernel (hardware-verified correct). New sync skeleton, ledger-verified:
//   tile kt = 4 phases; phase = {ds-read quadrant frags; stage 1 half-tile;
//   barrier; lgkmcnt(0); setprio+16 MFMA+setprio; barrier}.
//   Quadrants: P1=(mh0,nh0) reads aq(mh0)+bq0, P2=(mh0,nh1) reads bq1,
//   P3=(mh1,nh0) reads aq(mh1), P4=(mh1,nh1) reads nothing.
//   Stages: P1->Bhi(kt+1) other buf; P2->Ahi(kt+1) other buf;
//           P3->Blo(kt+2) CURRENT buf (B-reads of kt end in P2, sealed by
//           P2's post-barrier); P4->Alo(kt+2) CURRENT buf (A-reads end P3).
//   vmcnt(4) once per tile at P4 (before its barriers) = the 2 stage-pairs
//   issued after tile-(kt+1)'s last half was staged -> next tile guaranteed
//   landed, prefetch queue NEVER drained in steady state.
__global__ __launch_bounds__(512) void k_gemm256(const unsigned short* __restrict__ Xa,
                                                 const unsigned short* __restrict__ Wa,
                                                 float* __restrict__ out) {
  __shared__ unsigned short Asl[2][256 * 64];   // 64 KiB
  __shared__ unsigned short Bsl[2][256 * 64];   // 64 KiB
  int bid = blockIdx.x;                  // 256 blocks
  int xcd = bid & 7, idx = bid >> 3;     // bijective: 32 blocks per XCD
  int bm = (xcd * 4 + (idx >> 3)) * 256;
  int bn = (idx & 7) * 256;
  int w = threadIdx.x >> 6, lane = threadIdx.x & 63;
  int wm = (w >> 2) * 128;               // wave M offset (2 waves)
  int wn = (w & 3) * 64;                 // wave N offset (4 waves)
  int lrow = lane >> 3;
  int lcol_s = (lane & 7) << 3;
  int lcol_g = ((lane & 7) ^ (lrow & 7)) << 3;

  const unsigned short* gA = Xa + (size_t)(bm + w * 8 + lrow) * KAUG + lcol_g;
  const unsigned short* gB = Wa + (size_t)(bn + w * 8 + lrow) * KAUG + lcol_g;
  int sO = (w * 8 + lrow) * 64 + lcol_s;

  f32x4 acc[8][4] = {};
  bf16x8 aq[8];           // current mh quadrant: [f*2+ks]
  bf16x8 bq0[4], bq1[4];  // nh=0 / nh=1: [n*2+ks]

  // stage one HALF-tile (128 rows of one operand) of K-tile T into buf p: 2 gll
#define STG(arr, gp, p, T, h) do {                                                       \
    __builtin_amdgcn_global_load_lds(AS1(gp + (size_t)(2*(h)) * 64 * KAUG + (size_t)(T) * 64),   \
                                     AS3(&arr[p][0] + sO + (2*(h)) * 64 * 64), 16, 0, 0);\
    __builtin_amdgcn_global_load_lds(AS1(gp + (size_t)(2*(h)+1) * 64 * KAUG + (size_t)(T) * 64), \
                                     AS3(&arr[p][0] + sO + (2*(h)+1) * 64 * 64), 16, 0, 0);\
  } while (0)

#define DSR_A(p, MH) do {                                                                \
    _Pragma("unroll")                                                                    \
    for (int f = 0; f < 4; ++f)                                                          \
      _Pragma("unroll")                                                                  \
      for (int ks = 0; ks < 2; ++ks) {                                                   \
        int kch = ks * 4 + (lane >> 4);                                                  \
        int ko = ((kch ^ (lane & 7)) << 3);                                              \
        aq[f*2+ks] = *(const bf16x8*)(&Asl[p][0] + (wm + (MH)*64 + f*16 + (lane & 15)) * 64 + ko); \
      }                                                                                  \
  } while (0)

#define DSR_B(p, NH, bq) do {                                                            \
    _Pragma("unroll")                                                                    \
    for (int n = 0; n < 2; ++n)                                                          \
      _Pragma("unroll")                                                                  \
      for (int ks = 0; ks < 2; ++ks) {                                                   \
        int kch = ks * 4 + (lane >> 4);                                                  \
        int ko = ((kch ^ (lane & 7)) << 3);                                              \
        bq[n*2+ks] = *(const bf16x8*)(&Bsl[p][0] + (wn + (NH)*32 + n*16 + (lane & 15)) * 64 + ko); \
      }                                                                                  \
  } while (0)

#define MM(MH, NH, bq) do {                                                              \
    __builtin_amdgcn_s_setprio(1);                                                       \
    _Pragma("unroll")                                                                    \
    for (int ks = 0; ks < 2; ++ks)                                                       \
      _Pragma("unroll")                                                                  \
      for (int f = 0; f < 4; ++f)                                                        \
        _Pragma("unroll")                                                                \
        for (int n = 0; n < 2; ++n)                                                      \
          acc[(MH)*4+f][(NH)*2+n] = __builtin_amdgcn_mfma_f32_16x16x32_bf16(             \
              aq[f*2+ks], bq[n*2+ks], acc[(MH)*4+f][(NH)*2+n], 0, 0, 0);                 \
    __builtin_amdgcn_s_setprio(0);                                                       \
  } while (0)

#define BAR  __builtin_amdgcn_s_barrier()
#define WLG  asm volatile("s_waitcnt lgkmcnt(0)" ::: "memory")

#define TILE(p, T, S1, S2, S34, VMN) do {                                                \
    /* P1: (mh0,nh0) */                                                                  \
    DSR_A(p, 0); DSR_B(p, 0, bq0);                                                       \
    if (S1) STG(Bsl, gB, (p)^1, (T)+1, 1);                                               \
    BAR; WLG; MM(0, 0, bq0); BAR;                                                        \
    /* P2: (mh0,nh1) */                                                                  \
    DSR_B(p, 1, bq1);                                                                    \
    if (S2) STG(Asl, gA, (p)^1, (T)+1, 1);                                               \
    BAR; WLG; MM(0, 1, bq1); BAR;                                                        \
    /* P3: (mh1,nh0) — B-reads of tile T done (sealed by P2 barrier) */                  \
    DSR_A(p, 1);                                                                         \
    if (S34) STG(Bsl, gB, (p), (T)+2, 0);                                                \
    BAR; WLG; MM(1, 0, bq0); BAR;                                                        \
    /* P4: (mh1,nh1) — A-reads of tile T done (sealed by P3 barrier) */                  \
    if (S34) STG(Asl, gA, (p), (T)+2, 0);                                                \
    asm volatile("s_waitcnt vmcnt(" #VMN ")" ::: "memory");                              \
    BAR; WLG; MM(1, 1, bq1); BAR;                                                        \
  } while (0)

  // prologue: tile0 all 4 halves (buf0), tile1 lo halves (buf1); vmcnt(4) ->
  // tile0 landed (<=4 outstanding = tile1's 2 half-stages).
  STG(Bsl, gB, 0, 0, 0); STG(Asl, gA, 0, 0, 0);
  STG(Bsl, gB, 0, 0, 1); STG(Asl, gA, 0, 0, 1);
  STG(Bsl, gB, 1, 1, 0); STG(Asl, gA, 1, 1, 0);
  asm volatile("s_waitcnt vmcnt(4)" ::: "memory");
  BAR;

  // uniform: tiles 0..31 (stage targets reach tile 33, all in range)
  for (int kt = 0; kt < 32; kt += 2) {
    TILE(0, kt,     1, 1, 1, 4);
    TILE(1, kt + 1, 1, 1, 1, 4);
  }
  // peel: tile 32 (stage only tile33's hi halves), tile 33 (no stages)
  TILE(0, 32, 1, 1, 0, 0);
  TILE(1, 33, 0, 0, 0, 0);

#undef TILE
#undef MM
#undef DSR_A
#undef DSR_B
#undef STG
#undef BAR
#undef WLG

  // epilogue: same C/D mapping as proven R6 kernel (acc[F][N], F=mh*4+f, N=nh*2+n)
#pragma unroll
  for (int f = 0; f < 8; ++f) {
    int row = bm + wm + f * 16 + ((lane >> 4) << 2);
#pragma unroll
    for (int r = 0; r < 4; ++r) {
      float* orow = out + (size_t)(row + r) * OUTD + bn + wn + (lane & 15);
#pragma unroll
      for (int n = 0; n < 4; ++n) orow[n * 16] = acc[f][n][r];
    }
  }
}

extern "C" void kernel_launch(void* const* d_in, const int* in_sizes, int n_in,
                              void* d_out, int out_size, void* d_ws, size_t ws_size,
                              hipStream_t stream) {
  const float* x  = (const float*)d_in[0];
  const float* W  = (const float*)d_in[1];
  const float* gw = (const float*)d_in[2];
  const float* A  = (const float*)d_in[3];
  const float* B  = (const float*)d_in[4];
  float* out = (float*)d_out;

  char* ws = (char*)d_ws;
  unsigned short* Xa  = (unsigned short*)(ws);                  // 8192*2176*2 = 35,651,584
  unsigned short* Wa  = (unsigned short*)(ws + 35651584);       // 2048*2176*2 =  8,912,896
  unsigned short* Ag  = (unsigned short*)(ws + 44564480);       //  128*2048*2 =    524,288
  float*          wte = (float*)        (ws + 45088768);        // 8192*8*4    =    262,144
  // total 45,350,912 bytes

  k_prep   <<<3328, 512, 0, stream>>>(x, gw, W, B, A, Xa, wte, Wa, Ag);
  k_ha     <<<512, 256, 0, stream>>>(Xa, Ag, wte, Xa);
  k_gemm256<<<256, 512, 0, stream>>>(Xa, Wa, out);
}